// Round 9
// baseline (43.809 us; speedup 1.0000x reference)
//
#include <hip/hip_runtime.h>

// DeepPoly affine transformer — fused single pass over weight.
// Identity: Wp@x + Wm@y = 0.5*( W@(x+y) - |W|@(y-x) )
//           Wp@y + Wm@x = 0.5*( W@(x+y) + |W|@(y-x) )
// mu folded: new_lower = bias + sum( wp*A + wm*B ), A=beta*l0, B=lmbda*u0+mu
//            new_upper = bias + sum( wp*B + wm*A )
//
// R9: row-SEQUENTIAL W consumption (DRAM page locality): rows outer,
// chunks inner, so each block streams one contiguous 8KB row-slice at a
// time instead of interleaving 8 row-streams at 1KB granularity (all
// prior variants were pinned at 4.3-4.5 TB/s on the W stream; fillBuffer
// proves 7.2 TB/s one-directional is possible).  Latency hiding via a
// flat 16-item rolling register prefetch, depth 8 -> steady-state
// s_waitcnt vmcnt(7), never draining until the tail.  Cols live in LDS
// (planar layout, conflict-free), off the vmcnt FIFO.

constexpr int N_OUT  = 4096;
constexpr int N_IN   = 8192;
constexpr int BLK    = 256;             // 4 waves
constexpr int ROWS   = 8;               // output rows per block
constexpr int SPLITK = 4;
constexpr int KSLICE = N_IN / SPLITK;   // 2048 columns per block
constexpr int CHUNK  = BLK * 4;         // 1024 floats per chunk
constexpr int CPR    = KSLICE / CHUNK;  // 2 chunks per row-slice
constexpr int ITEMS  = ROWS * CPR;      // 16 sequential items per thread
constexpr int D      = 8;               // rolling prefetch depth
static_assert((D & (D - 1)) == 0 && D <= ITEMS, "power-of-2 depth");

__device__ __forceinline__ float4 ld4(const float* p) {
    return *reinterpret_cast<const float4*>(p);
}

__device__ __forceinline__ float waveRed(float v) {
#pragma unroll
    for (int off = 32; off > 0; off >>= 1)
        v += __shfl_xor(v, off, 64);
    return v;
}

// ---- pass 1: build the 4 fused column vectors into workspace ----
__global__ __launch_bounds__(256) void precompute_cols(
        const float* __restrict__ bounds,   // [2, N_IN]
        const float* __restrict__ bounds0,  // [2, N_IN]
        const float* __restrict__ beta,
        const float* __restrict__ lmbda,
        const float* __restrict__ mu,
        float* __restrict__ cols)           // [4, N_IN]
{
    const int i = blockIdx.x * 256 + threadIdx.x;
    if (i >= N_IN) return;
    const float l  = bounds[i],  u  = bounds[i + N_IN];
    const float l0 = bounds0[i], u0 = bounds0[i + N_IN];
    const float A  = beta[i] * l0;
    const float B  = fmaf(lmbda[i], u0, mu[i]);
    cols[i]             = l + u;   // s1
    cols[i + N_IN]      = u - l;   // d1  (>= 0)
    cols[i + 2 * N_IN]  = A + B;   // s2
    cols[i + 3 * N_IN]  = B - A;   // d2
}

// ---- pass 2: stream the weight once; write split-K partials ----
__global__ __launch_bounds__(BLK) void deeppoly_main(
        const float* __restrict__ W,
        const float* __restrict__ cols,
        float* __restrict__ partials)       // [SPLITK][N_OUT][4]
{
    __shared__ __align__(16) float lds[4 * KSLICE];   // 32 KB col slice
    __shared__ float red[BLK / 64][ROWS][4];

    const int t  = threadIdx.x;
    const int r0 = blockIdx.x * ROWS;
    const int sk = blockIdx.y;
    const int k0 = sk * KSLICE;

    // ---- stage the 4 col streams for this k-slice into LDS (once) ----
#pragma unroll
    for (int s = 0; s < 4; ++s) {
#pragma unroll
        for (int j = 0; j < CPR; ++j) {
            const int o = (j * BLK + t) * 4;
            *reinterpret_cast<float4*>(&lds[s * KSLICE + o]) =
                ld4(cols + s * N_IN + k0 + o);
        }
    }
    __syncthreads();

    // item i: row = i>>1, chunk = i&1 — strictly sequential W addresses
    const float* Wb = W + (size_t)r0 * N_IN + k0 + t * 4;
#define WADDR(i) (Wb + (size_t)((i) >> 1) * N_IN + ((i) & 1) * CHUNK)

    float4 buf[D];
#pragma unroll
    for (int i = 0; i < D; ++i)
        buf[i] = ld4(WADDR(i));

    float aS[ROWS], aD[ROWS], aMS[ROWS], aMD[ROWS];
#pragma unroll
    for (int r = 0; r < ROWS; ++r) {
        aS[r] = 0.f; aD[r] = 0.f; aMS[r] = 0.f; aMD[r] = 0.f;
    }

#define UPD(wc, s1c, d1c, s2c, d2c)                      \
    {                                                    \
        const float w_ = (wc);                           \
        const float a_ = fabsf(w_);                      \
        aS[r]  = fmaf(w_, (s1c), aS[r]);                 \
        aD[r]  = fmaf(a_, (d1c), aD[r]);                 \
        aMS[r] = fmaf(w_, (s2c), aMS[r]);                \
        aMD[r] = fmaf(a_, (d2c), aMD[r]);                \
    }

#pragma unroll
    for (int i = 0; i < ITEMS; ++i) {
        const float4 wv = buf[i & (D - 1)];          // waits vmcnt(D-1)
        if (i + D < ITEMS)
            buf[i & (D - 1)] = ld4(WADDR(i + D));    // refill slot

        const int r   = i >> 1;                      // compile-time const
        const int cof = (i & 1) * CHUNK + t * 4;
        const float4 s1v = *reinterpret_cast<const float4*>(&lds[0 * KSLICE + cof]);
        const float4 d1v = *reinterpret_cast<const float4*>(&lds[1 * KSLICE + cof]);
        const float4 s2v = *reinterpret_cast<const float4*>(&lds[2 * KSLICE + cof]);
        const float4 d2v = *reinterpret_cast<const float4*>(&lds[3 * KSLICE + cof]);

        UPD(wv.x, s1v.x, d1v.x, s2v.x, d2v.x)
        UPD(wv.y, s1v.y, d1v.y, s2v.y, d2v.y)
        UPD(wv.z, s1v.z, d1v.z, s2v.z, d2v.z)
        UPD(wv.w, s1v.w, d1v.w, s2v.w, d2v.w)
    }
#undef UPD
#undef WADDR

    // ---- block reduction: wave shuffle-reduce, then LDS across 4 waves ----
    const int wave = t >> 6;
    const int lane = t & 63;

#pragma unroll
    for (int r = 0; r < ROWS; ++r) {
        const float vS  = waveRed(aS[r]);
        const float vD  = waveRed(aD[r]);
        const float vMS = waveRed(aMS[r]);
        const float vMD = waveRed(aMD[r]);
        if (lane == 0) {
            red[wave][r][0] = vS;
            red[wave][r][1] = vD;
            red[wave][r][2] = vMS;
            red[wave][r][3] = vMD;
        }
    }
    __syncthreads();

    if (t < ROWS * 4) {
        const int r = t >> 2;
        const int s = t & 3;
        float acc = 0.f;
#pragma unroll
        for (int w = 0; w < BLK / 64; ++w)
            acc += red[w][r][s];
        partials[((size_t)sk * N_OUT + (r0 + r)) * 4 + s] = acc;
    }
}

// ---- pass 3: combine split-K partials + bias + tighter-bound select ----
__global__ __launch_bounds__(256) void deeppoly_epilogue(
        const float* __restrict__ partials, // [SPLITK][N_OUT][4]
        const float* __restrict__ bias,
        float* __restrict__ out)            // [2, N_OUT]
{
    const int i = blockIdx.x * 256 + threadIdx.x;
    if (i >= N_OUT) return;

    float4 p = ld4(partials + (size_t)i * 4);
#pragma unroll
    for (int sk = 1; sk < SPLITK; ++sk) {
        const float4 q = ld4(partials + ((size_t)sk * N_OUT + i) * 4);
        p.x += q.x; p.y += q.y; p.z += q.z; p.w += q.w;
    }
    const float bi = bias[i];
    const float lower     = fmaf(0.5f, p.x - p.y, bi);
    const float upper     = fmaf(0.5f, p.x + p.y, bi);
    const float new_lower = fmaf(0.5f, p.z - p.w, bi);
    const float new_upper = fmaf(0.5f, p.z + p.w, bi);

    out[i]         = fmaxf(lower, new_lower);
    out[N_OUT + i] = fminf(upper, new_upper);
}

extern "C" void kernel_launch(void* const* d_in, const int* in_sizes, int n_in,
                              void* d_out, int out_size, void* d_ws, size_t ws_size,
                              hipStream_t stream) {
    const float* W       = (const float*)d_in[0];
    const float* bias    = (const float*)d_in[1];
    const float* bounds  = (const float*)d_in[2];
    const float* bounds0 = (const float*)d_in[3];
    const float* beta    = (const float*)d_in[4];
    const float* lmbda   = (const float*)d_in[5];
    const float* mu      = (const float*)d_in[6];
    float* out      = (float*)d_out;
    float* cols     = (float*)d_ws;                 // 4*N_IN floats (128 KB)
    float* partials = (float*)d_ws + 4 * N_IN;      // SPLITK*N_OUT*4 floats (256 KB)

    precompute_cols<<<N_IN / 256, 256, 0, stream>>>(
        bounds, bounds0, beta, lmbda, mu, cols);

    dim3 grid(N_OUT / ROWS, SPLITK);
    deeppoly_main<<<grid, BLK, 0, stream>>>(W, cols, partials);

    deeppoly_epilogue<<<N_OUT / 256, 256, 0, stream>>>(partials, bias, out);
}

// Round 10
// 39.249 us; speedup vs baseline: 1.1162x; 1.1162x over previous
//
#include <hip/hip_runtime.h>

// DeepPoly affine transformer — fused single pass over weight.
// Identity: Wp@x + Wm@y = 0.5*( W@(x+y) - |W|@(y-x) )
//           Wp@y + Wm@x = 0.5*( W@(x+y) + |W|@(y-x) )
// mu folded: new_lower = bias + sum( wp*A + wm*B ), A=beta*l0, B=lmbda*u0+mu
//            new_upper = bias + sum( wp*B + wm*A )
//
// R10: ROWS=16 per BLOCK, 8 per THREAD.  R4's per-thread structure was the
// best performer (compiler-scheduled full unroll, acc=32 regs, 8 W-loads
// per chunk) — keep it bit-for-bit, and double rows-per-block by splitting
// rows across wave pairs (waves 0-1 -> rows 0-7, waves 2-3 -> rows 8-15).
// Both halves share one 32KB LDS col stage -> col delivery halves
// (201 -> 168 MB total).  Delivered-bytes model: best rounds all saturate
// ~7.2 TB/s combined; time scales with bytes.

constexpr int N_OUT  = 4096;
constexpr int N_IN   = 8192;
constexpr int BLK    = 256;             // 4 waves
constexpr int ROWS   = 16;              // rows per block
constexpr int TR     = 8;               // rows per thread (half-block)
constexpr int SPLITK = 4;
constexpr int KSLICE = N_IN / SPLITK;   // 2048 columns per block
constexpr int HTHR   = BLK / 2;         // 128 threads per row-half
constexpr int CHUNK  = HTHR * 4;        // 512 floats per chunk
constexpr int KITER  = KSLICE / CHUNK;  // 4 chunks per thread

__device__ __forceinline__ float4 ld4(const float* p) {
    return *reinterpret_cast<const float4*>(p);
}

__device__ __forceinline__ float waveRed(float v) {
#pragma unroll
    for (int off = 32; off > 0; off >>= 1)
        v += __shfl_xor(v, off, 64);
    return v;
}

// ---- pass 1: build the 4 fused column vectors into workspace ----
__global__ __launch_bounds__(256) void precompute_cols(
        const float* __restrict__ bounds,   // [2, N_IN]
        const float* __restrict__ bounds0,  // [2, N_IN]
        const float* __restrict__ beta,
        const float* __restrict__ lmbda,
        const float* __restrict__ mu,
        float* __restrict__ cols)           // [4, N_IN]
{
    const int i = blockIdx.x * 256 + threadIdx.x;
    if (i >= N_IN) return;
    const float l  = bounds[i],  u  = bounds[i + N_IN];
    const float l0 = bounds0[i], u0 = bounds0[i + N_IN];
    const float A  = beta[i] * l0;
    const float B  = fmaf(lmbda[i], u0, mu[i]);
    cols[i]             = l + u;   // s1
    cols[i + N_IN]      = u - l;   // d1  (>= 0)
    cols[i + 2 * N_IN]  = A + B;   // s2
    cols[i + 3 * N_IN]  = B - A;   // d2
}

// ---- pass 2: stream the weight once; write split-K partials ----
__global__ __launch_bounds__(BLK) void deeppoly_main(
        const float* __restrict__ W,
        const float* __restrict__ cols,
        float* __restrict__ partials)       // [SPLITK][N_OUT][4]
{
    __shared__ __align__(16) float lds[4 * KSLICE];   // 32 KB col slice
    __shared__ float red[BLK / 64][TR][4];

    const int t    = threadIdx.x;
    const int half = t >> 7;               // 0: rows 0-7, 1: rows 8-15
    const int th   = t & (HTHR - 1);       // index within the half
    const int r0   = blockIdx.x * ROWS + half * TR;
    const int sk   = blockIdx.y;
    const int k0   = sk * KSLICE;

    // ---- stage the 4 col streams into LDS (block-cooperative, once) ----
#pragma unroll
    for (int s = 0; s < 4; ++s) {
#pragma unroll
        for (int j = 0; j < KSLICE / (BLK * 4); ++j) {
            const int o = (j * BLK + t) * 4;
            *reinterpret_cast<float4*>(&lds[s * KSLICE + o]) =
                ld4(cols + s * N_IN + k0 + o);
        }
    }
    __syncthreads();

    const float* Wb = W + (size_t)r0 * N_IN + k0;

    float aS[TR], aD[TR], aMS[TR], aMD[TR];
#pragma unroll
    for (int r = 0; r < TR; ++r) {
        aS[r] = 0.f; aD[r] = 0.f; aMS[r] = 0.f; aMD[r] = 0.f;
    }

    // ---- R4-style compiler-scheduled full unroll ----
#pragma unroll
    for (int k = 0; k < KITER; ++k) {
        const int c = k * CHUNK + th * 4;

        const float4 s1v = *reinterpret_cast<const float4*>(&lds[0 * KSLICE + c]);
        const float4 d1v = *reinterpret_cast<const float4*>(&lds[1 * KSLICE + c]);
        const float4 s2v = *reinterpret_cast<const float4*>(&lds[2 * KSLICE + c]);
        const float4 d2v = *reinterpret_cast<const float4*>(&lds[3 * KSLICE + c]);

#pragma unroll
        for (int r = 0; r < TR; ++r) {
            const float4 wv = ld4(Wb + (size_t)r * N_IN + c);

#define UPD(wc, s1c, d1c, s2c, d2c)                      \
            {                                            \
                const float w_ = (wc);                   \
                const float a_ = fabsf(w_);              \
                aS[r]  = fmaf(w_, (s1c), aS[r]);         \
                aD[r]  = fmaf(a_, (d1c), aD[r]);         \
                aMS[r] = fmaf(w_, (s2c), aMS[r]);        \
                aMD[r] = fmaf(a_, (d2c), aMD[r]);        \
            }
            UPD(wv.x, s1v.x, d1v.x, s2v.x, d2v.x)
            UPD(wv.y, s1v.y, d1v.y, s2v.y, d2v.y)
            UPD(wv.z, s1v.z, d1v.z, s2v.z, d2v.z)
            UPD(wv.w, s1v.w, d1v.w, s2v.w, d2v.w)
#undef UPD
        }
    }

    // ---- reduction: wave shuffle-reduce, then combine wave pairs ----
    const int wave = t >> 6;                // waves 0,1: half 0; 2,3: half 1
    const int lane = t & 63;

#pragma unroll
    for (int r = 0; r < TR; ++r) {
        const float vS  = waveRed(aS[r]);
        const float vD  = waveRed(aD[r]);
        const float vMS = waveRed(aMS[r]);
        const float vMD = waveRed(aMD[r]);
        if (lane == 0) {
            red[wave][r][0] = vS;
            red[wave][r][1] = vD;
            red[wave][r][2] = vMS;
            red[wave][r][3] = vMD;
        }
    }
    __syncthreads();

    // 64 threads: r_glob = t>>2 in [0,16), stream s = t&3
    if (t < ROWS * 4) {
        const int rg = t >> 2;
        const int s  = t & 3;
        const int w0 = (rg >> 3) * 2;       // waves {0,1} or {2,3}
        const int rl = rg & 7;
        const float acc = red[w0][rl][s] + red[w0 + 1][rl][s];
        partials[((size_t)sk * N_OUT + (blockIdx.x * ROWS + rg)) * 4 + s] = acc;
    }
}

// ---- pass 3: combine split-K partials + bias + tighter-bound select ----
__global__ __launch_bounds__(256) void deeppoly_epilogue(
        const float* __restrict__ partials, // [SPLITK][N_OUT][4]
        const float* __restrict__ bias,
        float* __restrict__ out)            // [2, N_OUT]
{
    const int i = blockIdx.x * 256 + threadIdx.x;
    if (i >= N_OUT) return;

    float4 p = ld4(partials + (size_t)i * 4);
#pragma unroll
    for (int sk = 1; sk < SPLITK; ++sk) {
        const float4 q = ld4(partials + ((size_t)sk * N_OUT + i) * 4);
        p.x += q.x; p.y += q.y; p.z += q.z; p.w += q.w;
    }
    const float bi = bias[i];
    const float lower     = fmaf(0.5f, p.x - p.y, bi);
    const float upper     = fmaf(0.5f, p.x + p.y, bi);
    const float new_lower = fmaf(0.5f, p.z - p.w, bi);
    const float new_upper = fmaf(0.5f, p.z + p.w, bi);

    out[i]         = fmaxf(lower, new_lower);
    out[N_OUT + i] = fminf(upper, new_upper);
}

extern "C" void kernel_launch(void* const* d_in, const int* in_sizes, int n_in,
                              void* d_out, int out_size, void* d_ws, size_t ws_size,
                              hipStream_t stream) {
    const float* W       = (const float*)d_in[0];
    const float* bias    = (const float*)d_in[1];
    const float* bounds  = (const float*)d_in[2];
    const float* bounds0 = (const float*)d_in[3];
    const float* beta    = (const float*)d_in[4];
    const float* lmbda   = (const float*)d_in[5];
    const float* mu      = (const float*)d_in[6];
    float* out      = (float*)d_out;
    float* cols     = (float*)d_ws;                 // 4*N_IN floats (128 KB)
    float* partials = (float*)d_ws + 4 * N_IN;      // SPLITK*N_OUT*4 floats (256 KB)

    precompute_cols<<<N_IN / 256, 256, 0, stream>>>(
        bounds, bounds0, beta, lmbda, mu, cols);

    dim3 grid(N_OUT / ROWS, SPLITK);
    deeppoly_main<<<grid, BLK, 0, stream>>>(W, cols, partials);

    deeppoly_epilogue<<<N_OUT / 256, 256, 0, stream>>>(partials, bias, out);
}